// Round 14
// baseline (455.049 us; speedup 1.0000x reference)
//
#include <hip/hip_runtime.h>
#include <hip/hip_fp16.h>
#include <math.h>

// Problem constants (from reference file)
constexpr int N_NODES  = 50000;
constexpr int N_EDGES  = 1600000;
constexpr int G_GRAPHS = 64;
constexpr int D        = 32;
constexpr int D_ATTR   = 16;
constexpr int N_RBF    = 8;

// rw(len) lookup table: 8192 intervals over [0, LMAX], nearest-neighbor, fp16.
constexpr int   TBL      = 8192;
constexpr int   TBL_ROWS = TBL + 1;
constexpr float LMAX     = 10.0f;

// Final per-node bucket layout (SoA for coalesced conv reads). deg ~ Poisson(32).
constexpr int BUCKET = 80;

// dst-tiles of 64 nodes; per-tile contiguous streams filled by counting sort.
constexpr int NT     = 64;
constexpr int NTILES = (N_NODES + NT - 1) / NT;  // 782
constexpr int TCAP   = 2432;                     // Poisson(2048) +8.5 sigma
// Phase-1 chunking: 4096 edges/block (r12 best). r13 measured: 2048/block
// doubles occupancy but total time RISES (fixed per-block hist/scan cost) —
// scatter is at its write-pattern ceiling, not occupancy-bound.
constexpr int EPB    = 4096;
constexpr int NBLK1  = (N_EDGES + EPB - 1) / EPB;  // 391

constexpr int NSLOT = NTILES * NT * BUCKET;  // bucket slots total

typedef unsigned int  uint4v  __attribute__((ext_vector_type(4)));
typedef unsigned int  uint2v  __attribute__((ext_vector_type(2)));

__device__ __forceinline__ float silu(float x) {
    return x / (1.0f + __expf(-x));
}
__device__ __forceinline__ float h2f_bits(unsigned short u) {
    return __half2float(__ushort_as_half(u));
}

// ---------------------------------------------------------------------------
// 1) Node init: hm0 = h0@Wmsg0 (fp16); hs0 = h0@Wself0 + xattr@Wattr0 + b;
//    xa1/xa2 precomputed attr terms. Also zeroes tile_cursor and out
//    (replaces two memset dispatches).
// ---------------------------------------------------------------------------
__global__ void node_init_kernel(const int* __restrict__ x,
                                 const float* __restrict__ W_elem,
                                 const float* __restrict__ W0,
                                 const float* __restrict__ b0,
                                 const float* __restrict__ Wmsg0,
                                 const float* __restrict__ Wself0,
                                 const float* __restrict__ Wattr,
                                 const float* __restrict__ bconv,
                                 __half* __restrict__ hm0,
                                 float* __restrict__ hs0,
                                 float* __restrict__ xa1,
                                 float* __restrict__ xa2,
                                 int* __restrict__ tile_cursor,
                                 float* __restrict__ out) {
    int t = blockIdx.x * blockDim.x + threadIdx.x;
    if (t < NTILES) tile_cursor[t] = 0;
    if (t < G_GRAPHS) out[t] = 0.0f;
    int n = t >> 5, c = t & 31;
    if (n >= N_NODES) return;
    int sp = x[n];
    const float* we = W_elem + sp * D_ATTR;
    float xv = (c < D_ATTR) ? we[c] : 0.0f;
    float acc = b0[c];
#pragma unroll
    for (int a = 0; a < D_ATTR; ++a) acc += we[a] * W0[a * D + c];
    float m = 0.0f, s = 0.0f;
#pragma unroll
    for (int j = 0; j < D; ++j) {
        float hj = __shfl(acc, j, 32);
        m = fmaf(hj, Wmsg0[j * D + c], m);
        s = fmaf(hj, Wself0[j * D + c], s);
    }
    float a0 = bconv[0 * D + c], a1 = bconv[1 * D + c], a2 = bconv[2 * D + c];
#pragma unroll
    for (int j = 0; j < D_ATTR; ++j) {
        float xj = __shfl(xv, j, 32);
        a0 = fmaf(xj, Wattr[0 * D_ATTR * D + j * D + c], a0);
        a1 = fmaf(xj, Wattr[1 * D_ATTR * D + j * D + c], a1);
        a2 = fmaf(xj, Wattr[2 * D_ATTR * D + j * D + c], a2);
    }
    hm0[n * D + c] = __float2half(m);
    hs0[n * D + c] = s + a0;
    xa1[n * D + c] = a1;
    xa2[n * D + c] = a2;
}

// ---------------------------------------------------------------------------
// 2a) Phase 1: block-chunked counting sort into per-tile contiguous streams.
//     ONE 16 B AoS record per edge (SoA scatter = 3 dirty lines/edge — r11).
//     bin rec = { src | (tbl_idx<<16), dstLocal, sw0|sw1<<16, sw2 }
// ---------------------------------------------------------------------------
__global__ __launch_bounds__(256) void scatter_kernel(const int* __restrict__ eidx,
                                                      const float* __restrict__ pos,
                                                      const float* __restrict__ period,
                                                      const float* __restrict__ wsh,
                                                      int* __restrict__ tile_cursor,
                                                      uint4v* __restrict__ bins) {
    __shared__ int hist[NTILES];
    __shared__ int basev[NTILES];
    int tid = threadIdx.x;
    int e0 = blockIdx.x * EPB;
    for (int i = tid; i < NTILES; i += 256) hist[i] = 0;
    __syncthreads();
#pragma unroll 4
    for (int i = 0; i < EPB / 256; ++i) {
        int e = e0 + tid + 256 * i;
        if (e < N_EDGES) atomicAdd(&hist[eidx[N_EDGES + e] >> 6], 1);
    }
    __syncthreads();
    for (int t = tid; t < NTILES; t += 256) {
        int cnt = hist[t];
        basev[t] = (cnt > 0) ? atomicAdd(&tile_cursor[t], cnt) : 0;
        hist[t] = 0;
    }
    __syncthreads();
    for (int i = 0; i < EPB / 256; ++i) {
        int e = e0 + tid + 256 * i;
        if (e >= N_EDGES) continue;
        int s = eidx[e];
        int d = eidx[N_EDGES + e];
        float vx = pos[d * 3 + 0] - pos[s * 3 + 0] + period[e * 3 + 0];
        float vy = pos[d * 3 + 1] - pos[s * 3 + 1] + period[e * 3 + 1];
        float vz = pos[d * 3 + 2] - pos[s * 3 + 2] + period[e * 3 + 2];
        float len = sqrtf(vx * vx + vy * vy + vz * vz);
        float inv = 1.0f / (len + 1e-9f);
        int idx = (int)fminf(len * ((float)TBL / LMAX) + 0.5f, (float)TBL);
        float sw[3];
#pragma unroll
        for (int l = 0; l < 3; ++l)
            sw[l] = wsh[l * 4 + 0] + (vx * wsh[l * 4 + 1] + vy * wsh[l * 4 + 2] + vz * wsh[l * 4 + 3]) * inv;
        int tile = d >> 6;
        int rank = atomicAdd(&hist[tile], 1);
        int slot = basev[tile] + rank;
        if (slot < TCAP) {
            unsigned u0 = (unsigned)__half_as_ushort(__float2half(sw[0]));
            unsigned u1 = (unsigned)__half_as_ushort(__float2half(sw[1]));
            unsigned u2 = (unsigned)__half_as_ushort(__float2half(sw[2]));
            uint4v r;
            r.x = (unsigned)s | ((unsigned)idx << 16);
            r.y = (unsigned)(d & (NT - 1));
            r.z = u0 | (u1 << 16);
            r.w = u2;
            bins[(size_t)tile * TCAP + slot] = r;
        }
    }
}

// ---------------------------------------------------------------------------
// 2b) Phase 2: block-per-tile -> per-node bucket SoA:
//     xs[slot] = src|(idx<<16); swp[l*NSLOT + slot] = sw_l (ushort).
//     All writes land in the tile's L2-resident windows -> combined.
// ---------------------------------------------------------------------------
__global__ __launch_bounds__(256) void shuffle_kernel(const uint4v* __restrict__ bins,
                                                      const int* __restrict__ tile_cursor,
                                                      unsigned int* __restrict__ xs,
                                                      unsigned short* __restrict__ swp,
                                                      int* __restrict__ count) {
    __shared__ int lcur[NT];
    int tile = blockIdx.x;
    int tid = threadIdx.x;
    if (tid < NT) lcur[tid] = 0;
    __syncthreads();
    int cnt = tile_cursor[tile];
    if (cnt > TCAP) cnt = TCAP;
    const uint4v* base = bins + (size_t)tile * TCAP;
    for (int i = tid; i < cnt; i += 256) {
        uint4v r = __builtin_nontemporal_load(base + i);
        int dl = (int)(r.y & 63u);
        int slot = atomicAdd(&lcur[dl], 1);
        if (slot < BUCKET) {
            size_t g = (size_t)(tile * NT + dl) * BUCKET + slot;
            xs[g] = r.x;
            swp[0 * (size_t)NSLOT + g] = (unsigned short)(r.z & 0xFFFFu);
            swp[1 * (size_t)NSLOT + g] = (unsigned short)(r.z >> 16);
            swp[2 * (size_t)NSLOT + g] = (unsigned short)(r.w & 0xFFFFu);
        }
    }
    __syncthreads();
    if (tid < NT) {
        int node = tile * NT + tid;
        if (node < N_NODES) {
            int c = lcur[tid];
            count[node] = c < BUCKET ? c : BUCKET;
        }
    }
}

// ---------------------------------------------------------------------------
// 3) Build fp16 rw(len) tables for the 3 layers: table[l][idx][c]
// ---------------------------------------------------------------------------
__global__ void table_kernel(const float* __restrict__ Wr1,
                             const float* __restrict__ br1,
                             const float* __restrict__ Wr2,
                             __half* __restrict__ table) {
    int t = blockIdx.x * blockDim.x + threadIdx.x;
    if (t >= 3 * TBL_ROWS) return;
    int l = t / TBL_ROWS;
    int idx = t % TBL_ROWS;
    float len = (float)idx * (LMAX / (float)TBL);
    const float gamma = (8.0f / 5.0f) * (8.0f / 5.0f);  // (N_RBF/CUTOFF)^2
    float rbf[N_RBF];
#pragma unroll
    for (int k = 0; k < N_RBF; ++k) {
        float dd = len - (float)k * (5.0f / 7.0f);  // linspace(0, CUTOFF, 8)
        rbf[k] = __expf(-gamma * dd * dd);
    }
    float out[D];
#pragma unroll
    for (int c = 0; c < D; ++c) out[c] = 0.0f;
    for (int j = 0; j < D; ++j) {
        float z = br1[l * D + j];
#pragma unroll
        for (int k = 0; k < N_RBF; ++k) z += rbf[k] * Wr1[l * N_RBF * D + k * D + j];
        z = fmaxf(z, 0.0f);
        const float* w2 = Wr2 + l * D * D + j * D;
#pragma unroll
        for (int c = 0; c < D; ++c) out[c] += z * w2[c];
    }
    __half* dst = table + ((size_t)(l * TBL_ROWS + idx)) * D;
#pragma unroll
    for (int c = 0; c < D; ++c) dst[c] = __float2half(out[c]);
}

// ---------------------------------------------------------------------------
// 4) Conv layer (r12 edge loop — kept): wave-per-node, quarter-wave owns 4
//    consecutive slots per 16-slot chunk; one uint4 load = 4 slots' src|idx,
//    one uint2 load = their sw halves. Out-of-range slots select-zeroed.
//    Epilogues: NEXT -> shared-shfl double GEMM (hm/hs for next layer);
//    READOUT -> in-wave node MLP scalar + block-aggregated atomic (ONE
//    atomic per block of 4 nodes; r4 showed 50k per-node atomics onto 64
//    floats serialize at ~450 us).
// ---------------------------------------------------------------------------
template <int LAYER, bool NEXT, bool READOUT>
__global__ void conv_kernel(const __half* __restrict__ hm,
                            const float* __restrict__ hs,
                            const unsigned int* __restrict__ xs,
                            const unsigned short* __restrict__ swp,
                            const int* __restrict__ count,
                            const __half* __restrict__ table,
                            const float* __restrict__ Wmsg_next,
                            const float* __restrict__ Wself_next,
                            const float* __restrict__ xa_next,
                            __half* __restrict__ hm_out,
                            float* __restrict__ hs_out,
                            const int* __restrict__ batch,
                            const float* __restrict__ Wp1,
                            const float* __restrict__ bp1,
                            const float* __restrict__ Wp2,
                            const float* __restrict__ bp2,
                            float* __restrict__ out) {
    __shared__ float vnode[4];
    __shared__ int vbatch[4];
    int gtid = blockIdx.x * blockDim.x + threadIdx.x;
    int node = gtid >> 6;   // grid sized exactly: node < N_NODES always
    int lane = threadIdx.x & 63;
    int wid = threadIdx.x >> 6;
    int qw = lane >> 4;   // quarter id 0..3
    int q  = lane & 15;   // channel-pair id: channels {2q, 2q+1}

    const __half2* tab2 = (const __half2*)(table + ((size_t)LAYER * TBL_ROWS) * D);
    const __half2* hm2  = (const __half2*)hm;
    const unsigned short* swb = swp + (size_t)LAYER * NSLOT;
    int cnt = count[node];
    int beg = node * BUCKET;
    int end = beg + cnt;

    float ax = 0.0f, ay = 0.0f;
    for (int base = beg; base < end; base += 32) {
        int o0 = base + qw * 4;
        int o1 = o0 + 16;
        uint4v x0 = __builtin_nontemporal_load((const uint4v*)(xs + o0));
        uint4v x1 = __builtin_nontemporal_load((const uint4v*)(xs + o1));
        uint2v w0 = __builtin_nontemporal_load((const uint2v*)(swb + o0));
        uint2v w1 = __builtin_nontemporal_load((const uint2v*)(swb + o1));
        unsigned u[8];
        unsigned short wv[8];
        u[0] = x0.x; u[1] = x0.y; u[2] = x0.z; u[3] = x0.w;
        u[4] = x1.x; u[5] = x1.y; u[6] = x1.z; u[7] = x1.w;
        wv[0] = (unsigned short)(w0.x & 0xFFFFu); wv[1] = (unsigned short)(w0.x >> 16);
        wv[2] = (unsigned short)(w0.y & 0xFFFFu); wv[3] = (unsigned short)(w0.y >> 16);
        wv[4] = (unsigned short)(w1.x & 0xFFFFu); wv[5] = (unsigned short)(w1.x >> 16);
        wv[6] = (unsigned short)(w1.y & 0xFFFFu); wv[7] = (unsigned short)(w1.y >> 16);
#pragma unroll
        for (int j = 0; j < 8; ++j) {
            int slot = (j < 4) ? (o0 + j) : (o1 + j - 4);
            bool valid = slot < end;
            unsigned uu = valid ? u[j] : 0u;
            float sw = valid ? h2f_bits(wv[j]) : 0.0f;
            int s = (int)(uu & 0xFFFFu);
            int i = (int)(uu >> 16);
            float2 tf = __half22float2(tab2[i * 16 + q]);
            float2 mf = __half22float2(hm2[s * 16 + q]);
            ax = fmaf(tf.x * mf.x, sw, ax);
            ay = fmaf(tf.y * mf.y, sw, ay);
        }
    }
    ax += __shfl_xor(ax, 16);
    ax += __shfl_xor(ax, 32);
    ay += __shfl_xor(ay, 16);
    ay += __shfl_xor(ay, 32);

    int c = lane & 31;
    float vx = __shfl(ax, c >> 1);
    float vy = __shfl(ay, c >> 1);
    float agg = (c & 1) ? vy : vx;

    if ((lane >> 5) == 0) {
        float hn = silu(agg + hs[node * D + c]);
        if (NEXT) {
            float m = 0.0f, s2 = 0.0f;
#pragma unroll
            for (int j = 0; j < D; ++j) {
                float hj = __shfl(hn, j);
                m  = fmaf(hj, Wmsg_next[j * D + c], m);
                s2 = fmaf(hj, Wself_next[j * D + c], s2);
            }
            hm_out[node * D + c] = __float2half(m);
            hs_out[node * D + c] = s2 + xa_next[node * D + c];
        }
        if (READOUT) {
            // a_c = bp1[c] + sum_j hn_j Wp1[j][c] for c<16; v = silu(a)*Wp2[c]
            float a = (c < 16) ? bp1[c] : 0.0f;
#pragma unroll
            for (int j = 0; j < D; ++j) {
                float hj = __shfl(hn, j);
                float w = (c < 16) ? Wp1[j * 16 + c] : 0.0f;
                a = fmaf(hj, w, a);
            }
            float v = (c < 16) ? silu(a) * Wp2[c] : 0.0f;
#pragma unroll
            for (int o = 8; o > 0; o >>= 1) v += __shfl_down(v, o);
            if (c == 0) {
                vnode[wid] = v + bp2[0];
                vbatch[wid] = batch[node];
            }
        }
    }
    if (READOUT) {
        __syncthreads();
        if (threadIdx.x == 0) {
            int b0 = vbatch[0];
            bool uni = (vbatch[1] == b0) & (vbatch[2] == b0) & (vbatch[3] == b0);
            if (uni) {
                atomicAdd(out + b0, (vnode[0] + vnode[1]) + (vnode[2] + vnode[3]));
            } else {
#pragma unroll
                for (int k = 0; k < 4; ++k) atomicAdd(out + vbatch[k], vnode[k]);
            }
        }
    }
}

// ---------------------------------------------------------------------------
extern "C" void kernel_launch(void* const* d_in, const int* in_sizes, int n_in,
                              void* d_out, int out_size, void* d_ws, size_t ws_size,
                              hipStream_t stream) {
    const int*   x      = (const int*)d_in[0];
    const float* pos    = (const float*)d_in[1];
    const int*   eidx   = (const int*)d_in[2];
    const float* period = (const float*)d_in[3];
    const int*   batch  = (const int*)d_in[4];
    const float* W_elem = (const float*)d_in[5];
    const float* W0     = (const float*)d_in[6];
    const float* b0     = (const float*)d_in[7];
    const float* Wr1    = (const float*)d_in[8];
    const float* br1    = (const float*)d_in[9];
    const float* Wr2    = (const float*)d_in[10];
    const float* Wmsg   = (const float*)d_in[11];
    const float* Wattr  = (const float*)d_in[12];
    const float* Wself  = (const float*)d_in[13];
    const float* bconv  = (const float*)d_in[14];
    const float* wsh    = (const float*)d_in[15];
    const float* Wp1    = (const float*)d_in[16];
    const float* bp1    = (const float*)d_in[17];
    const float* Wp2    = (const float*)d_in[18];
    const float* bp2    = (const float*)d_in[19];

    char* base = (char*)d_ws;
    size_t off = 0;
    auto carve = [&](size_t bytes) -> void* {
        void* p = base + off;
        off = (off + bytes + 255) & ~(size_t)255;
        return p;
    };
    __half*         hm_a        = (__half*)carve((size_t)N_NODES * D * 2);
    __half*         hm_b        = (__half*)carve((size_t)N_NODES * D * 2);
    float*          hs_a        = (float*)carve((size_t)N_NODES * D * 4);
    float*          hs_b        = (float*)carve((size_t)N_NODES * D * 4);
    float*          xa1         = (float*)carve((size_t)N_NODES * D * 4);
    float*          xa2         = (float*)carve((size_t)N_NODES * D * 4);
    unsigned int*   xs          = (unsigned int*)carve((size_t)NSLOT * 4);
    unsigned short* swp         = (unsigned short*)carve((size_t)3 * NSLOT * 2);
    uint4v*         bins        = (uint4v*)carve((size_t)NTILES * TCAP * 16);
    int*            tile_cursor = (int*)carve((size_t)NTILES * 4);
    int*            count       = (int*)carve((size_t)NTILES * NT * 4);
    __half*         table       = (__half*)carve((size_t)3 * TBL_ROWS * D * 2);
    (void)ws_size; (void)in_sizes; (void)n_in; (void)out_size;

    node_init_kernel<<<(N_NODES * 32 + 255) / 256, 256, 0, stream>>>(
        x, W_elem, W0, b0, Wmsg + 0 * D * D, Wself + 0 * D * D, Wattr, bconv,
        hm_a, hs_a, xa1, xa2, tile_cursor, (float*)d_out);
    scatter_kernel<<<NBLK1, 256, 0, stream>>>(eidx, pos, period, wsh, tile_cursor, bins);
    table_kernel<<<(3 * TBL_ROWS + 127) / 128, 128, 0, stream>>>(Wr1, br1, Wr2, table);
    shuffle_kernel<<<NTILES, 256, 0, stream>>>(bins, tile_cursor, xs, swp, count);

    int cgrid = N_NODES * 64 / 256;  // 12500, exact
    conv_kernel<0, true, false><<<cgrid, 256, 0, stream>>>(
        hm_a, hs_a, xs, swp, count, table, Wmsg + 1 * D * D, Wself + 1 * D * D, xa1,
        hm_b, hs_b, nullptr, nullptr, nullptr, nullptr, nullptr, nullptr);
    conv_kernel<1, true, false><<<cgrid, 256, 0, stream>>>(
        hm_b, hs_b, xs, swp, count, table, Wmsg + 2 * D * D, Wself + 2 * D * D, xa2,
        hm_a, hs_a, nullptr, nullptr, nullptr, nullptr, nullptr, nullptr);
    conv_kernel<2, false, true><<<cgrid, 256, 0, stream>>>(
        hm_a, hs_a, xs, swp, count, table, nullptr, nullptr, nullptr,
        nullptr, nullptr, batch, Wp1, bp1, Wp2, bp2, (float*)d_out);
}

// Round 15
// 403.734 us; speedup vs baseline: 1.1271x; 1.1271x over previous
//
#include <hip/hip_runtime.h>
#include <hip/hip_fp16.h>
#include <math.h>

// Problem constants (from reference file)
constexpr int N_NODES  = 50000;
constexpr int N_EDGES  = 1600000;
constexpr int G_GRAPHS = 64;
constexpr int D        = 32;
constexpr int D_ATTR   = 16;
constexpr int N_RBF    = 8;

// rw(len) lookup table: 8192 intervals over [0, LMAX], nearest-neighbor, fp16.
constexpr int   TBL      = 8192;
constexpr int   TBL_ROWS = TBL + 1;
constexpr float LMAX     = 10.0f;

// Final per-node bucket layout (SoA for coalesced conv reads). deg ~ Poisson(32).
constexpr int BUCKET = 80;

// dst-tiles of 64 nodes; per-tile contiguous streams filled by counting sort.
constexpr int NT     = 64;
constexpr int NTILES = (N_NODES + NT - 1) / NT;  // 782
constexpr int TCAP   = 2432;                     // Poisson(2048) +8.5 sigma
// Phase-1 chunking: 4096 edges/block (r12 best; r13 showed 2048 regresses —
// fixed per-block hist/scan cost dominates; scatter is write-pattern-bound).
constexpr int EPB    = 4096;
constexpr int NBLK1  = (N_EDGES + EPB - 1) / EPB;  // 391

constexpr int NSLOT = NTILES * NT * BUCKET;  // bucket slots total

typedef unsigned int  uint4v  __attribute__((ext_vector_type(4)));
typedef unsigned int  uint2v  __attribute__((ext_vector_type(2)));

__device__ __forceinline__ float silu(float x) {
    return x / (1.0f + __expf(-x));
}
__device__ __forceinline__ float h2f_bits(unsigned short u) {
    return __half2float(__ushort_as_half(u));
}

// ---------------------------------------------------------------------------
// 1) Node init: hm0 = h0@Wmsg0 (fp16); hs0 = h0@Wself0 + xattr@Wattr0 + b;
//    xa1/xa2 precomputed attr terms. Also zeroes tile_cursor and out
//    (replaces two memset dispatches).
// ---------------------------------------------------------------------------
__global__ void node_init_kernel(const int* __restrict__ x,
                                 const float* __restrict__ W_elem,
                                 const float* __restrict__ W0,
                                 const float* __restrict__ b0,
                                 const float* __restrict__ Wmsg0,
                                 const float* __restrict__ Wself0,
                                 const float* __restrict__ Wattr,
                                 const float* __restrict__ bconv,
                                 __half* __restrict__ hm0,
                                 float* __restrict__ hs0,
                                 float* __restrict__ xa1,
                                 float* __restrict__ xa2,
                                 int* __restrict__ tile_cursor,
                                 float* __restrict__ out) {
    int t = blockIdx.x * blockDim.x + threadIdx.x;
    if (t < NTILES) tile_cursor[t] = 0;
    if (t < G_GRAPHS) out[t] = 0.0f;
    int n = t >> 5, c = t & 31;
    if (n >= N_NODES) return;
    int sp = x[n];
    const float* we = W_elem + sp * D_ATTR;
    float xv = (c < D_ATTR) ? we[c] : 0.0f;
    float acc = b0[c];
#pragma unroll
    for (int a = 0; a < D_ATTR; ++a) acc += we[a] * W0[a * D + c];
    float m = 0.0f, s = 0.0f;
#pragma unroll
    for (int j = 0; j < D; ++j) {
        float hj = __shfl(acc, j, 32);
        m = fmaf(hj, Wmsg0[j * D + c], m);
        s = fmaf(hj, Wself0[j * D + c], s);
    }
    float a0 = bconv[0 * D + c], a1 = bconv[1 * D + c], a2 = bconv[2 * D + c];
#pragma unroll
    for (int j = 0; j < D_ATTR; ++j) {
        float xj = __shfl(xv, j, 32);
        a0 = fmaf(xj, Wattr[0 * D_ATTR * D + j * D + c], a0);
        a1 = fmaf(xj, Wattr[1 * D_ATTR * D + j * D + c], a1);
        a2 = fmaf(xj, Wattr[2 * D_ATTR * D + j * D + c], a2);
    }
    hm0[n * D + c] = __float2half(m);
    hs0[n * D + c] = s + a0;
    xa1[n * D + c] = a1;
    xa2[n * D + c] = a2;
}

// ---------------------------------------------------------------------------
// 2a) Phase 1: block-chunked counting sort into per-tile contiguous streams.
//     ONE 16 B AoS record per edge (SoA scatter = 3 dirty lines/edge — r11).
//     bin rec = { src | (tbl_idx<<16), dstLocal, sw0|sw1<<16, sw2 }
// ---------------------------------------------------------------------------
__global__ __launch_bounds__(256) void scatter_kernel(const int* __restrict__ eidx,
                                                      const float* __restrict__ pos,
                                                      const float* __restrict__ period,
                                                      const float* __restrict__ wsh,
                                                      int* __restrict__ tile_cursor,
                                                      uint4v* __restrict__ bins) {
    __shared__ int hist[NTILES];
    __shared__ int basev[NTILES];
    int tid = threadIdx.x;
    int e0 = blockIdx.x * EPB;
    for (int i = tid; i < NTILES; i += 256) hist[i] = 0;
    __syncthreads();
#pragma unroll 4
    for (int i = 0; i < EPB / 256; ++i) {
        int e = e0 + tid + 256 * i;
        if (e < N_EDGES) atomicAdd(&hist[eidx[N_EDGES + e] >> 6], 1);
    }
    __syncthreads();
    for (int t = tid; t < NTILES; t += 256) {
        int cnt = hist[t];
        basev[t] = (cnt > 0) ? atomicAdd(&tile_cursor[t], cnt) : 0;
        hist[t] = 0;
    }
    __syncthreads();
    for (int i = 0; i < EPB / 256; ++i) {
        int e = e0 + tid + 256 * i;
        if (e >= N_EDGES) continue;
        int s = eidx[e];
        int d = eidx[N_EDGES + e];
        float vx = pos[d * 3 + 0] - pos[s * 3 + 0] + period[e * 3 + 0];
        float vy = pos[d * 3 + 1] - pos[s * 3 + 1] + period[e * 3 + 1];
        float vz = pos[d * 3 + 2] - pos[s * 3 + 2] + period[e * 3 + 2];
        float len = sqrtf(vx * vx + vy * vy + vz * vz);
        float inv = 1.0f / (len + 1e-9f);
        int idx = (int)fminf(len * ((float)TBL / LMAX) + 0.5f, (float)TBL);
        float sw[3];
#pragma unroll
        for (int l = 0; l < 3; ++l)
            sw[l] = wsh[l * 4 + 0] + (vx * wsh[l * 4 + 1] + vy * wsh[l * 4 + 2] + vz * wsh[l * 4 + 3]) * inv;
        int tile = d >> 6;
        int rank = atomicAdd(&hist[tile], 1);
        int slot = basev[tile] + rank;
        if (slot < TCAP) {
            unsigned u0 = (unsigned)__half_as_ushort(__float2half(sw[0]));
            unsigned u1 = (unsigned)__half_as_ushort(__float2half(sw[1]));
            unsigned u2 = (unsigned)__half_as_ushort(__float2half(sw[2]));
            uint4v r;
            r.x = (unsigned)s | ((unsigned)idx << 16);
            r.y = (unsigned)(d & (NT - 1));
            r.z = u0 | (u1 << 16);
            r.w = u2;
            bins[(size_t)tile * TCAP + slot] = r;
        }
    }
}

// ---------------------------------------------------------------------------
// 2b) Phase 2: block-per-tile -> per-node bucket SoA:
//     xs[slot] = src|(idx<<16); swp[l*NSLOT + slot] = sw_l (ushort).
//     All writes land in the tile's L2-resident windows -> combined.
// ---------------------------------------------------------------------------
__global__ __launch_bounds__(256) void shuffle_kernel(const uint4v* __restrict__ bins,
                                                      const int* __restrict__ tile_cursor,
                                                      unsigned int* __restrict__ xs,
                                                      unsigned short* __restrict__ swp,
                                                      int* __restrict__ count) {
    __shared__ int lcur[NT];
    int tile = blockIdx.x;
    int tid = threadIdx.x;
    if (tid < NT) lcur[tid] = 0;
    __syncthreads();
    int cnt = tile_cursor[tile];
    if (cnt > TCAP) cnt = TCAP;
    const uint4v* base = bins + (size_t)tile * TCAP;
    for (int i = tid; i < cnt; i += 256) {
        uint4v r = __builtin_nontemporal_load(base + i);
        int dl = (int)(r.y & 63u);
        int slot = atomicAdd(&lcur[dl], 1);
        if (slot < BUCKET) {
            size_t g = (size_t)(tile * NT + dl) * BUCKET + slot;
            xs[g] = r.x;
            swp[0 * (size_t)NSLOT + g] = (unsigned short)(r.z & 0xFFFFu);
            swp[1 * (size_t)NSLOT + g] = (unsigned short)(r.z >> 16);
            swp[2 * (size_t)NSLOT + g] = (unsigned short)(r.w & 0xFFFFu);
        }
    }
    __syncthreads();
    if (tid < NT) {
        int node = tile * NT + tid;
        if (node < N_NODES) {
            int c = lcur[tid];
            count[node] = c < BUCKET ? c : BUCKET;
        }
    }
}

// ---------------------------------------------------------------------------
// 3) Build fp16 rw(len) tables for the 3 layers: table[l][idx][c]
// ---------------------------------------------------------------------------
__global__ void table_kernel(const float* __restrict__ Wr1,
                             const float* __restrict__ br1,
                             const float* __restrict__ Wr2,
                             __half* __restrict__ table) {
    int t = blockIdx.x * blockDim.x + threadIdx.x;
    if (t >= 3 * TBL_ROWS) return;
    int l = t / TBL_ROWS;
    int idx = t % TBL_ROWS;
    float len = (float)idx * (LMAX / (float)TBL);
    const float gamma = (8.0f / 5.0f) * (8.0f / 5.0f);  // (N_RBF/CUTOFF)^2
    float rbf[N_RBF];
#pragma unroll
    for (int k = 0; k < N_RBF; ++k) {
        float dd = len - (float)k * (5.0f / 7.0f);  // linspace(0, CUTOFF, 8)
        rbf[k] = __expf(-gamma * dd * dd);
    }
    float out[D];
#pragma unroll
    for (int c = 0; c < D; ++c) out[c] = 0.0f;
    for (int j = 0; j < D; ++j) {
        float z = br1[l * D + j];
#pragma unroll
        for (int k = 0; k < N_RBF; ++k) z += rbf[k] * Wr1[l * N_RBF * D + k * D + j];
        z = fmaxf(z, 0.0f);
        const float* w2 = Wr2 + l * D * D + j * D;
#pragma unroll
        for (int c = 0; c < D; ++c) out[c] += z * w2[c];
    }
    __half* dst = table + ((size_t)(l * TBL_ROWS + idx)) * D;
#pragma unroll
    for (int c = 0; c < D; ++c) dst[c] = __float2half(out[c]);
}

// ---------------------------------------------------------------------------
// 4) Conv layer (r12 form): wave-per-node, quarter-wave owns 4 consecutive
//    slots per 16-slot chunk; one uint4 load = 4 slots' src|idx, one uint2
//    load = their sw halves. Out-of-range slots select-zeroed. No fused
//    readout (r14: 12.5k block-atomics onto 4 lines cost +51 us — per-line
//    atomic budget must stay in the hundreds).
// ---------------------------------------------------------------------------
template <int LAYER, bool NEXT>
__global__ void conv_kernel(const __half* __restrict__ hm,
                            const float* __restrict__ hs,
                            const unsigned int* __restrict__ xs,
                            const unsigned short* __restrict__ swp,
                            const int* __restrict__ count,
                            const __half* __restrict__ table,
                            const float* __restrict__ Wmsg_next,
                            const float* __restrict__ Wself_next,
                            const float* __restrict__ xa_next,
                            __half* __restrict__ hm_out,
                            float* __restrict__ hs_out,
                            float* __restrict__ h_final) {
    int gtid = blockIdx.x * blockDim.x + threadIdx.x;
    int node = gtid >> 6;
    if (node >= N_NODES) return;
    int lane = threadIdx.x & 63;
    int qw = lane >> 4;   // quarter id 0..3
    int q  = lane & 15;   // channel-pair id: channels {2q, 2q+1}

    const __half2* tab2 = (const __half2*)(table + ((size_t)LAYER * TBL_ROWS) * D);
    const __half2* hm2  = (const __half2*)hm;
    const unsigned short* swb = swp + (size_t)LAYER * NSLOT;
    int cnt = count[node];
    int beg = node * BUCKET;
    int end = beg + cnt;

    float ax = 0.0f, ay = 0.0f;
    for (int base = beg; base < end; base += 32) {
        int o0 = base + qw * 4;
        int o1 = o0 + 16;
        uint4v x0 = __builtin_nontemporal_load((const uint4v*)(xs + o0));
        uint4v x1 = __builtin_nontemporal_load((const uint4v*)(xs + o1));
        uint2v w0 = __builtin_nontemporal_load((const uint2v*)(swb + o0));
        uint2v w1 = __builtin_nontemporal_load((const uint2v*)(swb + o1));
        unsigned u[8];
        unsigned short wv[8];
        u[0] = x0.x; u[1] = x0.y; u[2] = x0.z; u[3] = x0.w;
        u[4] = x1.x; u[5] = x1.y; u[6] = x1.z; u[7] = x1.w;
        wv[0] = (unsigned short)(w0.x & 0xFFFFu); wv[1] = (unsigned short)(w0.x >> 16);
        wv[2] = (unsigned short)(w0.y & 0xFFFFu); wv[3] = (unsigned short)(w0.y >> 16);
        wv[4] = (unsigned short)(w1.x & 0xFFFFu); wv[5] = (unsigned short)(w1.x >> 16);
        wv[6] = (unsigned short)(w1.y & 0xFFFFu); wv[7] = (unsigned short)(w1.y >> 16);
#pragma unroll
        for (int j = 0; j < 8; ++j) {
            int slot = (j < 4) ? (o0 + j) : (o1 + j - 4);
            bool valid = slot < end;
            unsigned uu = valid ? u[j] : 0u;
            float sw = valid ? h2f_bits(wv[j]) : 0.0f;
            int s = (int)(uu & 0xFFFFu);
            int i = (int)(uu >> 16);
            float2 tf = __half22float2(tab2[i * 16 + q]);
            float2 mf = __half22float2(hm2[s * 16 + q]);
            ax = fmaf(tf.x * mf.x, sw, ax);
            ay = fmaf(tf.y * mf.y, sw, ay);
        }
    }
    ax += __shfl_xor(ax, 16);
    ax += __shfl_xor(ax, 32);
    ay += __shfl_xor(ay, 16);
    ay += __shfl_xor(ay, 32);

    int c = lane & 31;
    float vx = __shfl(ax, c >> 1);
    float vy = __shfl(ay, c >> 1);
    float agg = (c & 1) ? vy : vx;

    if ((lane >> 5) == 0) {
        float hn = silu(agg + hs[node * D + c]);
        if (NEXT) {
            float m = 0.0f, s2 = 0.0f;
#pragma unroll
            for (int j = 0; j < D; ++j) {
                float hj = __shfl(hn, j);
                m  = fmaf(hj, Wmsg_next[j * D + c], m);
                s2 = fmaf(hj, Wself_next[j * D + c], s2);
            }
            hm_out[node * D + c] = __float2half(m);
            hs_out[node * D + c] = s2 + xa_next[node * D + c];
        } else {
            h_final[node * D + c] = hn;
        }
    }
}

// ---------------------------------------------------------------------------
// 5) Readout: per-node MLP scalar, wave-aggregated segment-sum (batch sorted
//    -> ~782 wave-level atomics onto 64 floats — measured ~12 us).
// ---------------------------------------------------------------------------
__global__ void readout_kernel(const float* __restrict__ h,
                               const int* __restrict__ batch,
                               const float* __restrict__ Wp1,
                               const float* __restrict__ bp1,
                               const float* __restrict__ Wp2,
                               const float* __restrict__ bp2,
                               float* __restrict__ out) {
    int n = blockIdx.x * blockDim.x + threadIdx.x;
    float s = 0.0f;
    int b = -1;
    if (n < N_NODES) {
        b = batch[n];
        const float* hrow = h + n * D;
        float acc2 = bp2[0];
#pragma unroll
        for (int m = 0; m < 16; ++m) {
            float a = bp1[m];
#pragma unroll
            for (int j = 0; j < D; ++j) a += hrow[j] * Wp1[j * 16 + m];
            acc2 += silu(a) * Wp2[m];
        }
        s = acc2;  // SCALE=1, SHIFT=0 baked in
    }
    unsigned long long valid = __ballot(n < N_NODES);
    if (valid == 0ull) return;
    int firstLane = __ffsll(valid) - 1;
    int b0v = __shfl(b, firstLane);
    bool ok = (b == b0v) || (n >= N_NODES);
    if (__all(ok)) {
#pragma unroll
        for (int o = 32; o > 0; o >>= 1) s += __shfl_down(s, o);
        if ((threadIdx.x & 63) == 0) atomicAdd(out + b0v, s);
    } else {
        if (n < N_NODES) atomicAdd(out + b, s);
    }
}

// ---------------------------------------------------------------------------
extern "C" void kernel_launch(void* const* d_in, const int* in_sizes, int n_in,
                              void* d_out, int out_size, void* d_ws, size_t ws_size,
                              hipStream_t stream) {
    const int*   x      = (const int*)d_in[0];
    const float* pos    = (const float*)d_in[1];
    const int*   eidx   = (const int*)d_in[2];
    const float* period = (const float*)d_in[3];
    const int*   batch  = (const int*)d_in[4];
    const float* W_elem = (const float*)d_in[5];
    const float* W0     = (const float*)d_in[6];
    const float* b0     = (const float*)d_in[7];
    const float* Wr1    = (const float*)d_in[8];
    const float* br1    = (const float*)d_in[9];
    const float* Wr2    = (const float*)d_in[10];
    const float* Wmsg   = (const float*)d_in[11];
    const float* Wattr  = (const float*)d_in[12];
    const float* Wself  = (const float*)d_in[13];
    const float* bconv  = (const float*)d_in[14];
    const float* wsh    = (const float*)d_in[15];
    const float* Wp1    = (const float*)d_in[16];
    const float* bp1    = (const float*)d_in[17];
    const float* Wp2    = (const float*)d_in[18];
    const float* bp2    = (const float*)d_in[19];

    char* base = (char*)d_ws;
    size_t off = 0;
    auto carve = [&](size_t bytes) -> void* {
        void* p = base + off;
        off = (off + bytes + 255) & ~(size_t)255;
        return p;
    };
    __half*         hm_a        = (__half*)carve((size_t)N_NODES * D * 2);
    __half*         hm_b        = (__half*)carve((size_t)N_NODES * D * 2);
    float*          hs_a        = (float*)carve((size_t)N_NODES * D * 4);
    float*          hs_b        = (float*)carve((size_t)N_NODES * D * 4);
    float*          xa1         = (float*)carve((size_t)N_NODES * D * 4);
    float*          xa2         = (float*)carve((size_t)N_NODES * D * 4);
    float*          h_final     = (float*)carve((size_t)N_NODES * D * 4);
    unsigned int*   xs          = (unsigned int*)carve((size_t)NSLOT * 4);
    unsigned short* swp         = (unsigned short*)carve((size_t)3 * NSLOT * 2);
    uint4v*         bins        = (uint4v*)carve((size_t)NTILES * TCAP * 16);
    int*            tile_cursor = (int*)carve((size_t)NTILES * 4);
    int*            count       = (int*)carve((size_t)NTILES * NT * 4);
    __half*         table       = (__half*)carve((size_t)3 * TBL_ROWS * D * 2);
    (void)ws_size; (void)in_sizes; (void)n_in; (void)out_size;

    node_init_kernel<<<(N_NODES * 32 + 255) / 256, 256, 0, stream>>>(
        x, W_elem, W0, b0, Wmsg + 0 * D * D, Wself + 0 * D * D, Wattr, bconv,
        hm_a, hs_a, xa1, xa2, tile_cursor, (float*)d_out);
    scatter_kernel<<<NBLK1, 256, 0, stream>>>(eidx, pos, period, wsh, tile_cursor, bins);
    table_kernel<<<(3 * TBL_ROWS + 127) / 128, 128, 0, stream>>>(Wr1, br1, Wr2, table);
    shuffle_kernel<<<NTILES, 256, 0, stream>>>(bins, tile_cursor, xs, swp, count);

    int cgrid = (N_NODES * 64 + 255) / 256;
    conv_kernel<0, true><<<cgrid, 256, 0, stream>>>(
        hm_a, hs_a, xs, swp, count, table, Wmsg + 1 * D * D, Wself + 1 * D * D, xa1,
        hm_b, hs_b, nullptr);
    conv_kernel<1, true><<<cgrid, 256, 0, stream>>>(
        hm_b, hs_b, xs, swp, count, table, Wmsg + 2 * D * D, Wself + 2 * D * D, xa2,
        hm_a, hs_a, nullptr);
    conv_kernel<2, false><<<cgrid, 256, 0, stream>>>(
        hm_a, hs_a, xs, swp, count, table, nullptr, nullptr, nullptr,
        nullptr, nullptr, h_final);

    readout_kernel<<<(N_NODES + 255) / 256, 256, 0, stream>>>(h_final, batch, Wp1, bp1, Wp2, bp2,
                                                              (float*)d_out);
}